// Round 3
// baseline (1872.332 us; speedup 1.0000x reference)
//
#include <hip/hip_runtime.h>
#include <stdint.h>

#define N_ATOMS 100000
#define NS 4
#define NE 8
#define D0 384
#define D1 160
#define D2 128
#define D3 96
#define TM 32

// ---- workspace layout (bytes) ----
// hdr ints: [0..3] counts, [4..7] cursors, [8..11] padOff (atoms), [16..20] tileBase scan, [21] chunk
#define IDX_OFF_B 256
#define IDX_CAP (N_ATOMS + 4*TM)              // 100128 ints
#define W1B_OFF 400768                        // 256 + 100128*4, 16B aligned
#define W1_TOT (NS*NE*D0*D1)                  // 1966080
#define W2_TOT (NS*NE*D1*D2)                  // 655360
#define W3_TOT (NS*NE*D2*D3)                  // 393216
#define W2B_OFF (W1B_OFF + W1_TOT*2)          // 4332928
#define W3B_OFF (W2B_OFF + W2_TOT*2)          // 5643648

typedef __attribute__((ext_vector_type(8))) _Float16 h8v;
typedef __attribute__((ext_vector_type(4))) float f4v;

__device__ __forceinline__ unsigned short f2h(float x){
    _Float16 h = (_Float16)x;                 // hardware cvt, RNE
    return *(unsigned short*)&h;
}
__device__ __forceinline__ float h2f(unsigned short u){
    _Float16 h = *(_Float16*)&u;
    return (float)h;
}

// jax.nn.celu(x, 0.1) = x>0 ? x : 0.1*expm1(x/0.1)  -- NOTE the /alpha inside exp!
__device__ __forceinline__ float celu01(float v){
    return v > 0.f ? v : 0.1f * (__expf(fminf(v, 0.f) * 10.f) - 1.f);
}

__global__ void k_init(int* hdr, int* idx, float* out){
    int i = blockIdx.x * blockDim.x + threadIdx.x;
    if (i < IDX_CAP) idx[i] = 0;
    if (i < 8) hdr[i] = 0;
    if (i == 0) out[0] = 0.f;
}

__global__ void k_count(const int* __restrict__ species, int* __restrict__ hdr){
    int i = blockIdx.x * blockDim.x + threadIdx.x;
    if (i < N_ATOMS) atomicAdd(&hdr[species[i]], 1);
}

__global__ void k_scan(int* hdr){
    int pad = 0, tb = 0;
    hdr[16] = 0;
    for (int s = 0; s < 4; s++){
        hdr[8 + s] = pad;
        int tiles = (hdr[s] + TM - 1) / TM;
        pad += tiles * TM;
        tb  += tiles;
        hdr[17 + s] = tb;       // tileBase[s+1]; hdr[20] = total tiles
    }
    hdr[21] = (tb + 7) >> 3;    // tiles per XCD class
}

__global__ void k_scatter(const int* __restrict__ species, int* __restrict__ hdr,
                          int* __restrict__ idx){
    int i = blockIdx.x * blockDim.x + threadIdx.x;
    if (i < N_ATOMS){
        int s = species[i];
        int slot = atomicAdd(&hdr[4 + s], 1);
        idx[hdr[8 + s] + slot] = i;
    }
}

// Convert W1..W3 fp32 -> fp16 in MFMA-B-fragment order: [net][nt][kt][lane][j]
// element: k = kt*32 + (lane>>4)*8 + j ; n = nt*16 + (lane&15)
__global__ void k_convert(const float* __restrict__ W1, const float* __restrict__ W2,
                          const float* __restrict__ W3,
                          unsigned short* __restrict__ W1b, unsigned short* __restrict__ W2b,
                          unsigned short* __restrict__ W3b){
    int i = blockIdx.x * blockDim.x + threadIdx.x;
    if (i < W1_TOT){
        int net = i / (D0*D1);
        int r   = i % (D0*D1);
        int j = r & 7, lane = (r >> 3) & 63, kt = (r >> 9) % 12, nt = r / 6144;
        int k = kt*32 + (lane >> 4)*8 + j;
        int n = nt*16 + (lane & 15);
        W1b[i] = f2h(W1[(net*D0 + k)*D1 + n]);
    } else if (i < W1_TOT + W2_TOT){
        int i2 = i - W1_TOT;
        int net = i2 / (D1*D2);
        int r   = i2 % (D1*D2);
        int j = r & 7, lane = (r >> 3) & 63, kt = (r >> 9) % 5, nt = r / 2560;
        int k = kt*32 + (lane >> 4)*8 + j;
        int n = nt*16 + (lane & 15);
        W2b[i2] = f2h(W2[(net*D1 + k)*D2 + n]);
    } else if (i < W1_TOT + W2_TOT + W3_TOT){
        int i3 = i - W1_TOT - W2_TOT;
        int net = i3 / (D2*D3);
        int r   = i3 % (D2*D3);
        int j = r & 7, lane = (r >> 3) & 63, kt = (r >> 9) % 4, nt = r / 2048;
        int k = kt*32 + (lane >> 4)*8 + j;
        int n = nt*16 + (lane & 15);
        W3b[i3] = f2h(W3[(net*D2 + k)*D3 + n]);
    }
}

__global__ __launch_bounds__(256) void k_mlp(
    const float* __restrict__ aev, const int* __restrict__ hdr, const int* __restrict__ idx,
    const unsigned short* __restrict__ W1b, const unsigned short* __restrict__ W2b,
    const unsigned short* __restrict__ W3b,
    const float* __restrict__ b1, const float* __restrict__ b2, const float* __restrict__ b3,
    const float* __restrict__ W4, const float* __restrict__ b4, float* __restrict__ out)
{
    // padded strides: row-stride banks = {4,20,4,20} mod 32 -> only free 2-way conflicts
    __shared__ __align__(16) unsigned short sA [TM][392];
    __shared__ __align__(16) unsigned short sX1[TM][168];
    __shared__ __align__(16) unsigned short sX2[TM][136];
    __shared__ __align__(16) unsigned short sX3[TM][104];
    __shared__ float sRed[TM];

    int total = hdr[20];
    int chunk = hdr[21];
    int xcls = blockIdx.x & 7, j0 = blockIdx.x >> 3;
    if (j0 >= chunk) return;
    int tileId = xcls * chunk + j0;          // species-contiguous range per XCD class
    if (tileId >= total) return;

    int s = 0;
    while (s < 3 && tileId >= hdr[17 + s]) s++;
    int t      = tileId - hdr[16 + s];
    int count  = hdr[s];
    int rowBase = t * TM;
    const int* myIdx = idx + hdr[8 + s] + rowBase;

    int tid = threadIdx.x;

    // ---- stage AEV tile (fp32 -> fp16), gathered by species index ----
    {
        int row = tid >> 3, c8 = tid & 7;
        int atom = myIdx[row];
        const float4* src = (const float4*)(aev + (size_t)atom * D0);
        #pragma unroll
        for (int it = 0; it < 12; it++){
            int c4 = it*8 + c8;
            float4 v = src[c4];
            ushort4 o;
            o.x = f2h(v.x); o.y = f2h(v.y); o.z = f2h(v.z); o.w = f2h(v.w);
            *(ushort4*)&sA[row][c4*4] = o;
        }
    }
    __syncthreads();

    int lane = tid & 63, wid = tid >> 6;
    int m = lane & 15, quad = lane >> 4;
    int row4 = tid >> 3, p4 = tid & 7;
    float eAcc = 0.f;

    #pragma unroll 1
    for (int e = 0; e < NE; e++){
        int net = s * NE + e;

        // ---------- layer 1: sA [K=384] -> sX1 [N=160] ----------
        {
            h8v A[2][12];
            #pragma unroll
            for (int mt = 0; mt < 2; mt++)
                #pragma unroll
                for (int kt = 0; kt < 12; kt++)
                    A[mt][kt] = *(const h8v*)&sA[mt*16 + m][kt*32 + quad*8];
            const unsigned short* wf = W1b + (size_t)net * (D0*D1);
            for (int nt = wid; nt < 10; nt += 4){
                float bias = b1[net*D1 + nt*16 + m];
                f4v a0 = {bias, bias, bias, bias}, a1 = a0;
                const unsigned short* bp = wf + nt*6144 + lane*8;
                #pragma unroll
                for (int kt = 0; kt < 12; kt++){
                    h8v B = *(const h8v*)(bp + kt*512);
                    a0 = __builtin_amdgcn_mfma_f32_16x16x32_f16(A[0][kt], B, a0, 0, 0, 0);
                    a1 = __builtin_amdgcn_mfma_f32_16x16x32_f16(A[1][kt], B, a1, 0, 0, 0);
                }
                #pragma unroll
                for (int r = 0; r < 4; r++){
                    sX1[quad*4 + r][nt*16 + m] = f2h(celu01(a0[r]));
                    sX1[16 + quad*4 + r][nt*16 + m] = f2h(celu01(a1[r]));
                }
            }
        }
        __syncthreads();

        // ---------- layer 2: sX1 [K=160] -> sX2 [N=128] ----------
        {
            h8v A[2][5];
            #pragma unroll
            for (int mt = 0; mt < 2; mt++)
                #pragma unroll
                for (int kt = 0; kt < 5; kt++)
                    A[mt][kt] = *(const h8v*)&sX1[mt*16 + m][kt*32 + quad*8];
            const unsigned short* wf = W2b + (size_t)net * (D1*D2);
            for (int nt = wid; nt < 8; nt += 4){
                float bias = b2[net*D2 + nt*16 + m];
                f4v a0 = {bias, bias, bias, bias}, a1 = a0;
                const unsigned short* bp = wf + nt*2560 + lane*8;
                #pragma unroll
                for (int kt = 0; kt < 5; kt++){
                    h8v B = *(const h8v*)(bp + kt*512);
                    a0 = __builtin_amdgcn_mfma_f32_16x16x32_f16(A[0][kt], B, a0, 0, 0, 0);
                    a1 = __builtin_amdgcn_mfma_f32_16x16x32_f16(A[1][kt], B, a1, 0, 0, 0);
                }
                #pragma unroll
                for (int r = 0; r < 4; r++){
                    sX2[quad*4 + r][nt*16 + m] = f2h(celu01(a0[r]));
                    sX2[16 + quad*4 + r][nt*16 + m] = f2h(celu01(a1[r]));
                }
            }
        }
        __syncthreads();

        // ---------- layer 3: sX2 [K=128] -> sX3 [N=96] ----------
        {
            h8v A[2][4];
            #pragma unroll
            for (int mt = 0; mt < 2; mt++)
                #pragma unroll
                for (int kt = 0; kt < 4; kt++)
                    A[mt][kt] = *(const h8v*)&sX2[mt*16 + m][kt*32 + quad*8];
            const unsigned short* wf = W3b + (size_t)net * (D2*D3);
            for (int nt = wid; nt < 6; nt += 4){
                float bias = b3[net*D3 + nt*16 + m];
                f4v a0 = {bias, bias, bias, bias}, a1 = a0;
                const unsigned short* bp = wf + nt*2048 + lane*8;
                #pragma unroll
                for (int kt = 0; kt < 4; kt++){
                    h8v B = *(const h8v*)(bp + kt*512);
                    a0 = __builtin_amdgcn_mfma_f32_16x16x32_f16(A[0][kt], B, a0, 0, 0, 0);
                    a1 = __builtin_amdgcn_mfma_f32_16x16x32_f16(A[1][kt], B, a1, 0, 0, 0);
                }
                #pragma unroll
                for (int r = 0; r < 4; r++){
                    sX3[quad*4 + r][nt*16 + m] = f2h(celu01(a0[r]));
                    sX3[16 + quad*4 + r][nt*16 + m] = f2h(celu01(a1[r]));
                }
            }
        }
        __syncthreads();

        // ---------- layer 4: sX3 [K=96] -> scalar per row ----------
        {
            const float* w4 = W4 + net * D3;
            float sum = 0.f;
            #pragma unroll
            for (int jj = 0; jj < 12; jj++){
                int c = p4*12 + jj;
                sum += h2f(sX3[row4][c]) * w4[c];
            }
            sum += __shfl_down(sum, 4, 64);
            sum += __shfl_down(sum, 2, 64);
            sum += __shfl_down(sum, 1, 64);
            if (p4 == 0) eAcc += sum + b4[net];
        }
        __syncthreads();
    }

    if (p4 == 0){
        bool valid = (rowBase + row4) < count;
        sRed[row4] = valid ? eAcc * 0.125f : 0.f;   // ensemble mean (1/8)
    }
    __syncthreads();
    if (wid == 0){
        float v = (lane < TM) ? sRed[lane] : 0.f;
        v += __shfl_down(v, 32, 64);
        v += __shfl_down(v, 16, 64);
        v += __shfl_down(v,  8, 64);
        v += __shfl_down(v,  4, 64);
        v += __shfl_down(v,  2, 64);
        v += __shfl_down(v,  1, 64);
        if (lane == 0) atomicAdd(out, v);
    }
}

extern "C" void kernel_launch(void* const* d_in, const int* in_sizes, int n_in,
                              void* d_out, int out_size, void* d_ws, size_t ws_size,
                              hipStream_t stream){
    const float* aev     = (const float*)d_in[0];
    const int*   species = (const int*)  d_in[1];
    const float* W1 = (const float*)d_in[2];
    const float* b1 = (const float*)d_in[3];
    const float* W2 = (const float*)d_in[4];
    const float* b2 = (const float*)d_in[5];
    const float* W3 = (const float*)d_in[6];
    const float* b3 = (const float*)d_in[7];
    const float* W4 = (const float*)d_in[8];
    const float* b4 = (const float*)d_in[9];
    float* out = (float*)d_out;

    int* hdr = (int*)d_ws;
    int* idx = (int*)((char*)d_ws + IDX_OFF_B);
    unsigned short* W1b = (unsigned short*)((char*)d_ws + W1B_OFF);
    unsigned short* W2b = (unsigned short*)((char*)d_ws + W2B_OFF);
    unsigned short* W3b = (unsigned short*)((char*)d_ws + W3B_OFF);

    k_init   <<<(IDX_CAP + 255)/256, 256, 0, stream>>>(hdr, idx, out);
    k_count  <<<(N_ATOMS + 255)/256, 256, 0, stream>>>(species, hdr);
    k_scan   <<<1, 1, 0, stream>>>(hdr);
    k_scatter<<<(N_ATOMS + 255)/256, 256, 0, stream>>>(species, hdr, idx);
    int convTot = W1_TOT + W2_TOT + W3_TOT;
    k_convert<<<(convTot + 255)/256, 256, 0, stream>>>(W1, W2, W3, W1b, W2b, W3b);
    // 8 * ceil(maxTiles/8) = 3136 blocks covers worst-case 3129 tiles
    k_mlp    <<<3136, 256, 0, stream>>>(aev, hdr, idx, W1b, W2b, W3b,
                                        b1, b2, b3, W4, b4, out);
}

// Round 4
// 674.345 us; speedup vs baseline: 2.7765x; 2.7765x over previous
//
#include <hip/hip_runtime.h>
#include <stdint.h>

#define N_ATOMS 100000
#define NS 4
#define NE 8
#define D0 384
#define D1 160
#define D2 128
#define D3 96
#define TM 32
#define BUCKET_CAP 32768                      // >> max species count (~25.5k)

// ---- workspace layout (bytes) ----
// hdr ints: [0..3] cursors->counts, [8..11] bucket base (atoms), [16..20] tileBase scan, [21] chunk
#define IDX_OFF_B 256
#define IDX_CAP (NS*BUCKET_CAP)               // 131072 ints
#define W1B_OFF (IDX_OFF_B + IDX_CAP*4)       // 524544, 16B aligned
#define W1_TOT (NS*NE*D0*D1)                  // 1966080
#define W2_TOT (NS*NE*D1*D2)                  // 655360
#define W3_TOT (NS*NE*D2*D3)                  // 393216
#define W2B_OFF (W1B_OFF + W1_TOT*2)
#define W3B_OFF (W2B_OFF + W2_TOT*2)

typedef __attribute__((ext_vector_type(8))) _Float16 h8v;
typedef __attribute__((ext_vector_type(4))) float f4v;

__device__ __forceinline__ unsigned short f2h(float x){
    _Float16 h = (_Float16)x;                 // hardware cvt, RNE
    return *(unsigned short*)&h;
}
__device__ __forceinline__ float h2f(unsigned short u){
    _Float16 h = *(_Float16*)&u;
    return (float)h;
}

// jax.nn.celu(x, 0.1) = x>0 ? x : 0.1*expm1(x/0.1)  -- the /alpha inside exp!
__device__ __forceinline__ float celu01(float v){
    return v > 0.f ? v : 0.1f * (__expf(fminf(v, 0.f) * 10.f) - 1.f);
}

__global__ void k_init(int* hdr, int* idx, float* out){
    int i = blockIdx.x * blockDim.x + threadIdx.x;
    if (i < IDX_CAP) idx[i] = 0;
    if (i < 32) hdr[i] = 0;
    if (i == 0) out[0] = 0.f;
}

// Block-aggregated scatter: LDS histogram -> 4 global atomics per block.
__global__ __launch_bounds__(256) void k_scatter(const int* __restrict__ species,
                                                 int* __restrict__ hdr,
                                                 int* __restrict__ idx){
    __shared__ int lc[NS];
    __shared__ int lb[NS];
    int tid = threadIdx.x;
    if (tid < NS) lc[tid] = 0;
    __syncthreads();
    int i = blockIdx.x * 256 + tid;
    int s = 0, r = 0;
    bool valid = (i < N_ATOMS);
    if (valid){
        s = species[i];
        r = atomicAdd(&lc[s], 1);             // LDS atomic: local rank
    }
    __syncthreads();
    if (tid < NS) lb[tid] = atomicAdd(&hdr[tid], lc[tid]);  // 4 global atomics/block
    __syncthreads();
    if (valid) idx[s * BUCKET_CAP + lb[s] + r] = i;
}

__global__ void k_scan(int* hdr){
    int tb = 0;
    hdr[16] = 0;
    for (int s = 0; s < 4; s++){
        hdr[8 + s] = s * BUCKET_CAP;          // bucket base (atom slots)
        int tiles = (hdr[s] + TM - 1) / TM;
        tb += tiles;
        hdr[17 + s] = tb;                     // tileBase[s+1]; hdr[20] = total tiles
    }
    hdr[21] = (tb + 7) >> 3;                  // tiles per XCD class
}

// Convert W1..W3 fp32 -> fp16 in MFMA-B-fragment order: [net][nt][kt][lane][j]
// element: k = kt*32 + (lane>>4)*8 + j ; n = nt*16 + (lane&15)
__global__ void k_convert(const float* __restrict__ W1, const float* __restrict__ W2,
                          const float* __restrict__ W3,
                          unsigned short* __restrict__ W1b, unsigned short* __restrict__ W2b,
                          unsigned short* __restrict__ W3b){
    int i = blockIdx.x * blockDim.x + threadIdx.x;
    if (i < W1_TOT){
        int net = i / (D0*D1);
        int r   = i % (D0*D1);
        int j = r & 7, lane = (r >> 3) & 63, kt = (r >> 9) % 12, nt = r / 6144;
        int k = kt*32 + (lane >> 4)*8 + j;
        int n = nt*16 + (lane & 15);
        W1b[i] = f2h(W1[(net*D0 + k)*D1 + n]);
    } else if (i < W1_TOT + W2_TOT){
        int i2 = i - W1_TOT;
        int net = i2 / (D1*D2);
        int r   = i2 % (D1*D2);
        int j = r & 7, lane = (r >> 3) & 63, kt = (r >> 9) % 5, nt = r / 2560;
        int k = kt*32 + (lane >> 4)*8 + j;
        int n = nt*16 + (lane & 15);
        W2b[i2] = f2h(W2[(net*D1 + k)*D2 + n]);
    } else if (i < W1_TOT + W2_TOT + W3_TOT){
        int i3 = i - W1_TOT - W2_TOT;
        int net = i3 / (D2*D3);
        int r   = i3 % (D2*D3);
        int j = r & 7, lane = (r >> 3) & 63, kt = (r >> 9) % 4, nt = r / 2048;
        int k = kt*32 + (lane >> 4)*8 + j;
        int n = nt*16 + (lane & 15);
        W3b[i3] = f2h(W3[(net*D2 + k)*D3 + n]);
    }
}

__global__ __launch_bounds__(256) void k_mlp(
    const float* __restrict__ aev, const int* __restrict__ hdr, const int* __restrict__ idx,
    const unsigned short* __restrict__ W1b, const unsigned short* __restrict__ W2b,
    const unsigned short* __restrict__ W3b,
    const float* __restrict__ b1, const float* __restrict__ b2, const float* __restrict__ b3,
    const float* __restrict__ W4, const float* __restrict__ b4, float* __restrict__ out)
{
    // padded strides: row-stride banks = {4,20,4,20} mod 32 -> only free 2-way conflicts
    __shared__ __align__(16) unsigned short sA [TM][392];
    __shared__ __align__(16) unsigned short sX1[TM][168];
    __shared__ __align__(16) unsigned short sX2[TM][136];
    __shared__ __align__(16) unsigned short sX3[TM][104];
    __shared__ float sRed[TM];

    int total = hdr[20];
    int chunk = hdr[21];
    int xcls = blockIdx.x & 7, j0 = blockIdx.x >> 3;
    if (j0 >= chunk) return;
    int tileId = xcls * chunk + j0;          // species-contiguous range per XCD class
    if (tileId >= total) return;

    int s = 0;
    while (s < 3 && tileId >= hdr[17 + s]) s++;
    int t      = tileId - hdr[16 + s];
    int count  = hdr[s];
    int rowBase = t * TM;
    const int* myIdx = idx + hdr[8 + s] + rowBase;

    int tid = threadIdx.x;

    // ---- stage AEV tile (fp32 -> fp16), gathered by species index ----
    {
        int row = tid >> 3, c8 = tid & 7;
        int atom = myIdx[row];
        const float4* src = (const float4*)(aev + (size_t)atom * D0);
        #pragma unroll
        for (int it = 0; it < 12; it++){
            int c4 = it*8 + c8;
            float4 v = src[c4];
            ushort4 o;
            o.x = f2h(v.x); o.y = f2h(v.y); o.z = f2h(v.z); o.w = f2h(v.w);
            *(ushort4*)&sA[row][c4*4] = o;
        }
    }
    __syncthreads();

    int lane = tid & 63, wid = tid >> 6;
    int m = lane & 15, quad = lane >> 4;
    int row4 = tid >> 3, p4 = tid & 7;
    float eAcc = 0.f;

    #pragma unroll 1
    for (int e = 0; e < NE; e++){
        int net = s * NE + e;

        // ---------- layer 1: sA [K=384] -> sX1 [N=160] ----------
        {
            h8v A[2][12];
            #pragma unroll
            for (int mt = 0; mt < 2; mt++)
                #pragma unroll
                for (int kt = 0; kt < 12; kt++)
                    A[mt][kt] = *(const h8v*)&sA[mt*16 + m][kt*32 + quad*8];
            const unsigned short* wf = W1b + (size_t)net * (D0*D1);
            for (int nt = wid; nt < 10; nt += 4){
                float bias = b1[net*D1 + nt*16 + m];
                f4v a0 = {bias, bias, bias, bias}, a1 = a0;
                const unsigned short* bp = wf + nt*6144 + lane*8;
                #pragma unroll
                for (int kt = 0; kt < 12; kt++){
                    h8v B = *(const h8v*)(bp + kt*512);
                    a0 = __builtin_amdgcn_mfma_f32_16x16x32_f16(A[0][kt], B, a0, 0, 0, 0);
                    a1 = __builtin_amdgcn_mfma_f32_16x16x32_f16(A[1][kt], B, a1, 0, 0, 0);
                }
                #pragma unroll
                for (int r = 0; r < 4; r++){
                    sX1[quad*4 + r][nt*16 + m] = f2h(celu01(a0[r]));
                    sX1[16 + quad*4 + r][nt*16 + m] = f2h(celu01(a1[r]));
                }
            }
        }
        __syncthreads();

        // ---------- layer 2: sX1 [K=160] -> sX2 [N=128] ----------
        {
            h8v A[2][5];
            #pragma unroll
            for (int mt = 0; mt < 2; mt++)
                #pragma unroll
                for (int kt = 0; kt < 5; kt++)
                    A[mt][kt] = *(const h8v*)&sX1[mt*16 + m][kt*32 + quad*8];
            const unsigned short* wf = W2b + (size_t)net * (D1*D2);
            for (int nt = wid; nt < 8; nt += 4){
                float bias = b2[net*D2 + nt*16 + m];
                f4v a0 = {bias, bias, bias, bias}, a1 = a0;
                const unsigned short* bp = wf + nt*2560 + lane*8;
                #pragma unroll
                for (int kt = 0; kt < 5; kt++){
                    h8v B = *(const h8v*)(bp + kt*512);
                    a0 = __builtin_amdgcn_mfma_f32_16x16x32_f16(A[0][kt], B, a0, 0, 0, 0);
                    a1 = __builtin_amdgcn_mfma_f32_16x16x32_f16(A[1][kt], B, a1, 0, 0, 0);
                }
                #pragma unroll
                for (int r = 0; r < 4; r++){
                    sX2[quad*4 + r][nt*16 + m] = f2h(celu01(a0[r]));
                    sX2[16 + quad*4 + r][nt*16 + m] = f2h(celu01(a1[r]));
                }
            }
        }
        __syncthreads();

        // ---------- layer 3: sX2 [K=128] -> sX3 [N=96] ----------
        {
            h8v A[2][4];
            #pragma unroll
            for (int mt = 0; mt < 2; mt++)
                #pragma unroll
                for (int kt = 0; kt < 4; kt++)
                    A[mt][kt] = *(const h8v*)&sX2[mt*16 + m][kt*32 + quad*8];
            const unsigned short* wf = W3b + (size_t)net * (D2*D3);
            for (int nt = wid; nt < 6; nt += 4){
                float bias = b3[net*D3 + nt*16 + m];
                f4v a0 = {bias, bias, bias, bias}, a1 = a0;
                const unsigned short* bp = wf + nt*2048 + lane*8;
                #pragma unroll
                for (int kt = 0; kt < 4; kt++){
                    h8v B = *(const h8v*)(bp + kt*512);
                    a0 = __builtin_amdgcn_mfma_f32_16x16x32_f16(A[0][kt], B, a0, 0, 0, 0);
                    a1 = __builtin_amdgcn_mfma_f32_16x16x32_f16(A[1][kt], B, a1, 0, 0, 0);
                }
                #pragma unroll
                for (int r = 0; r < 4; r++){
                    sX3[quad*4 + r][nt*16 + m] = f2h(celu01(a0[r]));
                    sX3[16 + quad*4 + r][nt*16 + m] = f2h(celu01(a1[r]));
                }
            }
        }
        __syncthreads();

        // ---------- layer 4: sX3 [K=96] -> scalar per row ----------
        {
            const float* w4 = W4 + net * D3;
            float sum = 0.f;
            #pragma unroll
            for (int jj = 0; jj < 12; jj++){
                int c = p4*12 + jj;
                sum += h2f(sX3[row4][c]) * w4[c];
            }
            sum += __shfl_down(sum, 4, 64);
            sum += __shfl_down(sum, 2, 64);
            sum += __shfl_down(sum, 1, 64);
            if (p4 == 0) eAcc += sum + b4[net];
        }
        __syncthreads();
    }

    if (p4 == 0){
        bool valid = (rowBase + row4) < count;
        sRed[row4] = valid ? eAcc * 0.125f : 0.f;   // ensemble mean (1/8)
    }
    __syncthreads();
    if (wid == 0){
        float v = (lane < TM) ? sRed[lane] : 0.f;
        v += __shfl_down(v, 32, 64);
        v += __shfl_down(v, 16, 64);
        v += __shfl_down(v,  8, 64);
        v += __shfl_down(v,  4, 64);
        v += __shfl_down(v,  2, 64);
        v += __shfl_down(v,  1, 64);
        if (lane == 0) atomicAdd(out, v);
    }
}

extern "C" void kernel_launch(void* const* d_in, const int* in_sizes, int n_in,
                              void* d_out, int out_size, void* d_ws, size_t ws_size,
                              hipStream_t stream){
    const float* aev     = (const float*)d_in[0];
    const int*   species = (const int*)  d_in[1];
    const float* W1 = (const float*)d_in[2];
    const float* b1 = (const float*)d_in[3];
    const float* W2 = (const float*)d_in[4];
    const float* b2 = (const float*)d_in[5];
    const float* W3 = (const float*)d_in[6];
    const float* b3 = (const float*)d_in[7];
    const float* W4 = (const float*)d_in[8];
    const float* b4 = (const float*)d_in[9];
    float* out = (float*)d_out;

    int* hdr = (int*)d_ws;
    int* idx = (int*)((char*)d_ws + IDX_OFF_B);
    unsigned short* W1b = (unsigned short*)((char*)d_ws + W1B_OFF);
    unsigned short* W2b = (unsigned short*)((char*)d_ws + W2B_OFF);
    unsigned short* W3b = (unsigned short*)((char*)d_ws + W3B_OFF);

    k_init   <<<(IDX_CAP + 255)/256, 256, 0, stream>>>(hdr, idx, out);
    k_scatter<<<(N_ATOMS + 255)/256, 256, 0, stream>>>(species, hdr, idx);
    k_scan   <<<1, 1, 0, stream>>>(hdr);
    int convTot = W1_TOT + W2_TOT + W3_TOT;
    k_convert<<<(convTot + 255)/256, 256, 0, stream>>>(W1, W2, W3, W1b, W2b, W3b);
    // 8 * ceil(maxTiles/8) = 3136 blocks covers worst-case 3128 tiles
    k_mlp    <<<3136, 256, 0, stream>>>(aev, hdr, idx, W1b, W2b, W3b,
                                        b1, b2, b3, W4, b4, out);
}